// Round 5
// baseline (649.194 us; speedup 1.0000x reference)
//
#include <hip/hip_runtime.h>

#define NEG_SLOPE 0.2f

__device__ __forceinline__ float leaky1(float e) { return e > 0.f ? e : NEG_SLOPE * e; }

__device__ __forceinline__ unsigned short f2bf(float f) {
    unsigned u = __float_as_uint(f);
    u += 0x7fffu + ((u >> 16) & 1u);
    return (unsigned short)(u >> 16);
}

// ================= CSR build (bucketed, write-local) =================
#define EPB 16384  // edges per block in P1/P2

__global__ __launch_bounds__(256) void bucket_count(const int* __restrict__ dst,
                                                    int* __restrict__ counts,
                                                    int* __restrict__ gcnt,
                                                    int* __restrict__ relBase,
                                                    int E, int N, int NB) {
    __shared__ int hist[256];
    int t = threadIdx.x, blk = blockIdx.x;
    if (t < NB) hist[t] = 0;
    __syncthreads();
    int e0 = blk * EPB + t;
#pragma unroll 4
    for (int k = 0; k < EPB / 256; ++k) {
        int e = e0 + k * 256;
        if (e < E) {
            int d = dst[e];
            if ((unsigned)d < (unsigned)N) {
                atomicAdd(&counts[d], 1);
                atomicAdd(&hist[d >> 9], 1);
            }
        }
    }
    __syncthreads();
    if (t < NB) relBase[blk * NB + t] = atomicAdd(&gcnt[t], hist[t]);
}

__global__ __launch_bounds__(256) void scan_buckets(const int* __restrict__ gcnt,
                                                    int* __restrict__ gboff, int NB) {
    __shared__ int sm[256];
    int t = threadIdx.x;
    int v = (t < NB) ? gcnt[t] : 0;
    sm[t] = v;
    __syncthreads();
#pragma unroll
    for (int o = 1; o < 256; o <<= 1) {
        int u = (t >= o) ? sm[t - o] : 0;
        __syncthreads();
        sm[t] += u;
        __syncthreads();
    }
    if (t < NB) gboff[t] = sm[t] - v;
    if (t == NB - 1) gboff[NB] = sm[t];
}

__global__ __launch_bounds__(256) void bucket_scatter(const int* __restrict__ src,
                                                      const int* __restrict__ dst,
                                                      const int* __restrict__ gboff,
                                                      const int* __restrict__ relBase,
                                                      int2* __restrict__ eb,
                                                      int E, int N, int NB) {
    __shared__ int cur[256];
    int t = threadIdx.x, blk = blockIdx.x;
    if (t < NB) cur[t] = gboff[t] + relBase[blk * NB + t];
    __syncthreads();
    int e0 = blk * EPB + t;
#pragma unroll 4
    for (int k = 0; k < EPB / 256; ++k) {
        int e = e0 + k * 256;
        if (e < E) {
            int d = dst[e];
            if ((unsigned)d < (unsigned)N) {
                int pos = atomicAdd(&cur[d >> 9], 1);
                eb[pos] = make_int2(src[e], d);
            }
        }
    }
}

__global__ __launch_bounds__(256) void csr_scatter(const int2* __restrict__ eb,
                                                   const int* __restrict__ gboff,
                                                   const int* __restrict__ offs,
                                                   int* __restrict__ csr) {
    __shared__ int ncur[512];
    int t = threadIdx.x, b = blockIdx.x;
    ncur[t] = 0; ncur[t + 256] = 0;
    __syncthreads();
    int s0 = gboff[b], s1 = gboff[b + 1];
    for (int e = s0 + t; e < s1; e += 256) {
        int2 p = eb[e];
        int pos = offs[p.y] + atomicAdd(&ncur[p.y & 511], 1);
        csr[pos] = p.x;
    }
}

// ---- hierarchical exclusive scan of counts[N] -> offs[N] (+ offs[N]=E) ----

__global__ __launch_bounds__(256) void scan_partial(const int* __restrict__ counts,
                                                    int* __restrict__ blockSums, int N) {
    __shared__ int sm[256];
    int b = blockIdx.x, t = threadIdx.x;
    int i0 = (b << 10) + (t << 2);
    int s = 0;
    if (i0 + 3 < N) {
        int4 v = *(const int4*)(counts + i0);
        s = v.x + v.y + v.z + v.w;
    } else {
#pragma unroll
        for (int j = 0; j < 4; ++j)
            if (i0 + j < N) s += counts[i0 + j];
    }
    sm[t] = s;
    __syncthreads();
#pragma unroll
    for (int o = 128; o > 0; o >>= 1) {
        if (t < o) sm[t] += sm[t + o];
        __syncthreads();
    }
    if (t == 0) blockSums[b] = sm[0];
}

__global__ __launch_bounds__(128) void scan_blocksums(const int* __restrict__ blockSums,
                                                      int* __restrict__ blockOffs, int nb) {
    __shared__ int sm[128];
    int t = threadIdx.x;
    int v = (t < nb) ? blockSums[t] : 0;
    sm[t] = v;
    __syncthreads();
#pragma unroll
    for (int o = 1; o < 128; o <<= 1) {
        int u = (t >= o) ? sm[t - o] : 0;
        __syncthreads();
        sm[t] += u;
        __syncthreads();
    }
    if (t < nb) blockOffs[t] = sm[t] - v;
}

__global__ __launch_bounds__(256) void scan_offs(const int* __restrict__ counts,
                                                 const int* __restrict__ blockOffs,
                                                 int* __restrict__ offs, int N, int E) {
    __shared__ int sm[256];
    int b = blockIdx.x, t = threadIdx.x;
    int i0 = (b << 10) + (t << 2);
    int c[4];
    int s = 0;
#pragma unroll
    for (int j = 0; j < 4; ++j) {
        c[j] = (i0 + j < N) ? counts[i0 + j] : 0;
        s += c[j];
    }
    sm[t] = s;
    __syncthreads();
#pragma unroll
    for (int o = 1; o < 256; o <<= 1) {
        int u = (t >= o) ? sm[t - o] : 0;
        __syncthreads();
        sm[t] += u;
        __syncthreads();
    }
    int run = blockOffs[b] + sm[t] - s;
#pragma unroll
    for (int j = 0; j < 4; ++j) {
        if (i0 + j < N) offs[i0 + j] = run;
        run += c[j];
    }
    if (b == 0 && t == 0) offs[N] = E;
}

// ================= Dense GEMM (+optional bf16 mirror) =================

__global__ __launch_bounds__(256) void gemm128(const float* __restrict__ X,
                                               const float* __restrict__ W,
                                               float* __restrict__ OUT,
                                               unsigned short* __restrict__ HB,
                                               const float* __restrict__ bias,
                                               int accumulate) {
    __shared__ float Xs[32][128];
    __shared__ float Ws[64][128];
    int t = threadIdx.x;
    int row0 = blockIdx.x << 5;
    {
        const float4* xg = (const float4*)(X + (size_t)row0 * 128);
        float4* xs = (float4*)&Xs[0][0];
#pragma unroll
        for (int i = 0; i < 4; ++i) xs[t + 256 * i] = xg[t + 256 * i];
    }
    int cx = t & 31, ry = t >> 5;
    int c0 = cx << 2, r0 = ry << 2;
    float acc[4][4] = {};
#pragma unroll 1
    for (int ph = 0; ph < 2; ++ph) {
        __syncthreads();
        {
            const float4* wg = (const float4*)(W + (size_t)ph * 64 * 128);
            float4* ws = (float4*)&Ws[0][0];
#pragma unroll
            for (int i = 0; i < 8; ++i) ws[t + 256 * i] = wg[t + 256 * i];
        }
        __syncthreads();
#pragma unroll 4
        for (int k4 = 0; k4 < 16; ++k4) {
            float4 a[4], b[4];
#pragma unroll
            for (int i = 0; i < 4; ++i)
                a[i] = *(const float4*)&Xs[r0 + i][(ph << 6) + (k4 << 2)];
#pragma unroll
            for (int kk = 0; kk < 4; ++kk)
                b[kk] = *(const float4*)&Ws[(k4 << 2) + kk][c0];
#pragma unroll
            for (int i = 0; i < 4; ++i) {
                acc[i][0] = fmaf(a[i].x, b[0].x, acc[i][0]);
                acc[i][1] = fmaf(a[i].x, b[0].y, acc[i][1]);
                acc[i][2] = fmaf(a[i].x, b[0].z, acc[i][2]);
                acc[i][3] = fmaf(a[i].x, b[0].w, acc[i][3]);
                acc[i][0] = fmaf(a[i].y, b[1].x, acc[i][0]);
                acc[i][1] = fmaf(a[i].y, b[1].y, acc[i][1]);
                acc[i][2] = fmaf(a[i].y, b[1].z, acc[i][2]);
                acc[i][3] = fmaf(a[i].y, b[1].w, acc[i][3]);
                acc[i][0] = fmaf(a[i].z, b[2].x, acc[i][0]);
                acc[i][1] = fmaf(a[i].z, b[2].y, acc[i][1]);
                acc[i][2] = fmaf(a[i].z, b[2].z, acc[i][2]);
                acc[i][3] = fmaf(a[i].z, b[2].w, acc[i][3]);
                acc[i][0] = fmaf(a[i].w, b[3].x, acc[i][0]);
                acc[i][1] = fmaf(a[i].w, b[3].y, acc[i][1]);
                acc[i][2] = fmaf(a[i].w, b[3].z, acc[i][2]);
                acc[i][3] = fmaf(a[i].w, b[3].w, acc[i][3]);
            }
        }
    }
    float4 bv = make_float4(0.f, 0.f, 0.f, 0.f);
    if (bias) bv = *(const float4*)&bias[c0];
#pragma unroll
    for (int i = 0; i < 4; ++i) {
        size_t row = (size_t)(row0 + r0 + i);
        float* op = OUT + row * 128 + c0;
        float4 o;
        o.x = acc[i][0] + bv.x;
        o.y = acc[i][1] + bv.y;
        o.z = acc[i][2] + bv.z;
        o.w = acc[i][3] + bv.w;
        if (accumulate) {
            float4 old = *(const float4*)op;
            o.x += old.x; o.y += old.y; o.z += old.z; o.w += old.w;
        }
        *(float4*)op = o;
        if (HB) {
            ushort4 hv;
            hv.x = f2bf(o.x); hv.y = f2bf(o.y); hv.z = f2bf(o.z); hv.w = f2bf(o.w);
            *(ushort4*)(HB + row * 128 + c0) = hv;
        }
    }
}

// ============ attention scores per node (SoA by head) ============

__global__ __launch_bounds__(256) void s_kernel(const float* __restrict__ h,
                                                const float* __restrict__ a_s,
                                                const float* __restrict__ a_d,
                                                float* __restrict__ sSt,
                                                float* __restrict__ sDt, int N) {
    int gid = blockIdx.x * 256 + threadIdx.x;
    if (gid >= N * 4) return;
    int n = gid >> 2, hd = gid & 3;
    const float* hp = h + (size_t)n * 128 + hd * 32;
    const float* as = a_s + hd * 32;
    const float* ad = a_d + hd * 32;
    float ss = 0.f, sd = 0.f;
#pragma unroll
    for (int c = 0; c < 32; ++c) {
        float v = hp[c];
        ss = fmaf(v, as[c], ss);
        sd = fmaf(v, ad[c], sd);
    }
    sSt[(size_t)hd * N + n] = ss;
    sDt[(size_t)hd * N + n] = sd;
}

// ============ fused softmax-weight + gather-accumulate (v4) ============
// One wave per dst node. Consumer role: cl = lane&31 owns channels 4cl..4cl+3
// (head hd = cl>>3); half = lane>>5 picks edge i+half of each pair -> per pair:
// 1 dwordx2 gather (512B/wave, both rows), 2 bpermute, 4 unpack, 4 fma.
// Weight role: lane = whead*16+sub computes w(edge lo+sub, whead); consumers
// fetch via shfl(w, hd*16+i+half) (index <= hd*16+15; zero-w lanes cover tails).
// No max-subtraction: |scores| <~ 2, exp safe, softmax shift-invariant.

__global__ __launch_bounds__(256) void agg4_kernel(const float* __restrict__ h,
                                                   const unsigned short* __restrict__ hb,
                                                   const float* __restrict__ sSt,
                                                   const float* __restrict__ sDt,
                                                   const int* __restrict__ offs,
                                                   const int* __restrict__ csr,
                                                   const float* __restrict__ bias,
                                                   float* __restrict__ out,
                                                   int do_relu, int N) {
    int n = (blockIdx.x << 2) + (threadIdx.x >> 6);
    if (n >= N) return;
    int lane = threadIdx.x & 63;
    int half = lane >> 5;
    int cl = lane & 31;
    int hd = cl >> 3;          // consumer head
    int whead = lane >> 4;     // weight-role head
    int sub = lane & 15;

    size_t wb = (size_t)whead * N;
    float sdh = sDt[wb + n];
    float selfw = __expf(leaky1(sSt[wb + n] + sdh));   // uniform within weight group

    float4 acc = make_float4(0.f, 0.f, 0.f, 0.f);
    float wsum = 0.f;

    int off = offs[n], end = offs[n + 1];
    for (int base = off; base < end; base += 64) {
        int idx = base + lane;
        int spre = (idx < end) ? csr[idx] : 0;
        int cnt = min(64, end - base);
#pragma unroll 1
        for (int lo = 0; lo < cnt; lo += 16) {
            // weight for edge base+lo+sub, head whead
            float w = 0.f;
            {
                int s2 = __shfl(spre, lo + sub);
                if (lo + sub < cnt) w = __expf(leaky1(sSt[wb + s2] + sdh));
            }
            wsum += w;
            int c2 = min(16, cnt - lo);
#pragma unroll 2
            for (int i = 0; i < c2; i += 2) {
                int sj = __shfl(spre, lo + i + half);
                float wj = __shfl(w, (hd << 4) + i + half);   // 0 for tail lanes
                uint2 v = *(const uint2*)(hb + (size_t)sj * 128 + 4 * cl);
                acc.x = fmaf(wj, __uint_as_float(v.x << 16), acc.x);
                acc.y = fmaf(wj, __uint_as_float(v.x & 0xffff0000u), acc.y);
                acc.z = fmaf(wj, __uint_as_float(v.y << 16), acc.z);
                acc.w = fmaf(wj, __uint_as_float(v.y & 0xffff0000u), acc.w);
            }
        }
    }
    // merge edge-halves
    acc.x += __shfl_xor(acc.x, 32);
    acc.y += __shfl_xor(acc.y, 32);
    acc.z += __shfl_xor(acc.z, 32);
    acc.w += __shfl_xor(acc.w, 32);
    // reduce wsum within each 16-lane weight group
#pragma unroll
    for (int o = 8; o > 0; o >>= 1) wsum += __shfl_xor(wsum, o);
    float denom = wsum + selfw;                 // uniform across weight group
    float iv = 1.0f / __shfl(denom, hd << 4);   // pick own head's denom
    float sw = __shfl(selfw, hd << 4);

    if (half == 0) {
        float4 hs = *(const float4*)(h + (size_t)n * 128 + 4 * cl);
        float4 bv = *(const float4*)(bias + 4 * cl);
        float4 o;
        o.x = fmaf(fmaf(sw, hs.x, acc.x), iv, bv.x);
        o.y = fmaf(fmaf(sw, hs.y, acc.y), iv, bv.y);
        o.z = fmaf(fmaf(sw, hs.z, acc.z), iv, bv.z);
        o.w = fmaf(fmaf(sw, hs.w, acc.w), iv, bv.w);
        if (do_relu) {
            o.x = fmaxf(o.x, 0.f); o.y = fmaxf(o.y, 0.f);
            o.z = fmaxf(o.z, 0.f); o.w = fmaxf(o.w, 0.f);
        }
        *(float4*)(out + (size_t)n * 128 + 4 * cl) = o;
    }
}

// ================= host =================

extern "C" void kernel_launch(void* const* d_in, const int* in_sizes, int n_in,
                              void* d_out, int out_size, void* d_ws, size_t ws_size,
                              hipStream_t stream) {
    const float* x   = (const float*)d_in[0];
    const int*   ei  = (const int*)d_in[1];
    const float* W1  = (const float*)d_in[2];
    const float* a1s = (const float*)d_in[3];
    const float* a1d = (const float*)d_in[4];
    const float* b1  = (const float*)d_in[5];
    const float* W2  = (const float*)d_in[6];
    const float* a2s = (const float*)d_in[7];
    const float* a2d = (const float*)d_in[8];
    const float* b2  = (const float*)d_in[9];
    const float* Wr  = (const float*)d_in[10];
    const float* br  = (const float*)d_in[11];
    float* out = (float*)d_out;

    int N = in_sizes[0] / 128;
    int E = in_sizes[1] / 2;
    const int* src = ei;
    const int* dst = ei + E;
    int NB = (N + 511) >> 9;
    int ebl = (E + EPB - 1) / EPB;

    char* w = (char*)d_ws;
    size_t p = 0;
    auto take = [&](size_t bytes) -> char* {
        char* r = w + p;
        p = (p + bytes + 255) & ~(size_t)255;
        return r;
    };
    float* bufA = (float*)take((size_t)N * 128 * 4);
    float* bufB = (float*)take((size_t)N * 128 * 4);
    unsigned short* hb = (unsigned short*)take((size_t)N * 128 * 2);
    float* sSt  = (float*)take((size_t)N * 4 * 4);
    float* sDt  = (float*)take((size_t)N * 4 * 4);
    int* counts = (int*)take((size_t)N * 4);
    int* gcnt   = (int*)take((size_t)256 * 4);
    int* offs   = (int*)take((size_t)(N + 1) * 4);
    int* gboff  = (int*)take((size_t)257 * 4);
    int* bsums  = (int*)take((size_t)256 * 4);
    int* boffs  = (int*)take((size_t)256 * 4);
    int* relBase = (int*)take((size_t)ebl * NB * 4);
    int2* eb    = (int2*)take((size_t)E * 8);
    int* csr    = (int*)take((size_t)E * 4);

    hipMemsetAsync(counts, 0, (size_t)N * 4, stream);
    hipMemsetAsync(gcnt, 0, 256 * 4, stream);

    int nb = (N + 1023) / 1024;

    bucket_count<<<ebl, 256, 0, stream>>>(dst, counts, gcnt, relBase, E, N, NB);
    scan_partial<<<nb, 256, 0, stream>>>(counts, bsums, N);
    scan_blocksums<<<1, 128, 0, stream>>>(bsums, boffs, nb);
    scan_offs<<<nb, 256, 0, stream>>>(counts, boffs, offs, N, E);
    scan_buckets<<<1, 256, 0, stream>>>(gcnt, gboff, NB);
    bucket_scatter<<<ebl, 256, 0, stream>>>(src, dst, gboff, relBase, eb, E, N, NB);
    csr_scatter<<<NB, 256, 0, stream>>>(eb, gboff, offs, csr);

    int gb = N / 32;
    int sb = (N * 4 + 255) / 256;
    int ab = (N + 3) / 4;

    // layer 1
    gemm128<<<gb, 256, 0, stream>>>(x, W1, bufA, hb, nullptr, 0);
    s_kernel<<<sb, 256, 0, stream>>>(bufA, a1s, a1d, sSt, sDt, N);
    agg4_kernel<<<ab, 256, 0, stream>>>(bufA, hb, sSt, sDt, offs, csr, b1, bufB, 1, N);
    // layer 2
    gemm128<<<gb, 256, 0, stream>>>(bufB, W2, bufA, hb, nullptr, 0);
    s_kernel<<<sb, 256, 0, stream>>>(bufA, a2s, a2d, sSt, sDt, N);
    agg4_kernel<<<ab, 256, 0, stream>>>(bufA, hb, sSt, sDt, offs, csr, b2, out, 0, N);
    // residual: out += x @ Wr + br
    gemm128<<<gb, 256, 0, stream>>>(x, Wr, out, nullptr, br, 1);
}

// Round 6
// 487.755 us; speedup vs baseline: 1.3310x; 1.3310x over previous
//
#include <hip/hip_runtime.h>

#define NEG_SLOPE 0.2f

__device__ __forceinline__ float leaky1(float e) { return e > 0.f ? e : NEG_SLOPE * e; }

__device__ __forceinline__ unsigned short f2bf(float f) {
    unsigned u = __float_as_uint(f);
    u += 0x7fffu + ((u >> 16) & 1u);
    return (unsigned short)(u >> 16);
}

// ================= CSR build (bucketed, write-local) =================
#define EPB 4096   // edges per block in P1/P2 (391 blocks at E=1.6M)

// P1: per-bucket histogram (LDS) + per-block reserved base within each bucket.
__global__ __launch_bounds__(256) void bucket_hist(const int* __restrict__ dst,
                                                   int* __restrict__ gcnt,
                                                   int* __restrict__ relBase,
                                                   int E, int N, int NB) {
    __shared__ int hist[256];
    int t = threadIdx.x, blk = blockIdx.x;
    if (t < NB) hist[t] = 0;
    __syncthreads();
    int e0 = blk * EPB + t;
#pragma unroll 4
    for (int k = 0; k < EPB / 256; ++k) {
        int e = e0 + k * 256;
        if (e < E) {
            int d = dst[e];
            if ((unsigned)d < (unsigned)N) atomicAdd(&hist[d >> 9], 1);
        }
    }
    __syncthreads();
    if (t < NB) relBase[blk * NB + t] = atomicAdd(&gcnt[t], hist[t]);
}

__global__ __launch_bounds__(256) void scan_buckets(const int* __restrict__ gcnt,
                                                    int* __restrict__ gboff, int NB) {
    __shared__ int sm[256];
    int t = threadIdx.x;
    int v = (t < NB) ? gcnt[t] : 0;
    sm[t] = v;
    __syncthreads();
#pragma unroll
    for (int o = 1; o < 256; o <<= 1) {
        int u = (t >= o) ? sm[t - o] : 0;
        __syncthreads();
        sm[t] += u;
        __syncthreads();
    }
    if (t < NB) gboff[t] = sm[t] - v;
    if (t == NB - 1) gboff[NB] = sm[t];
}

// P2: scatter (src,dst) pairs into bucket-contiguous order.
__global__ __launch_bounds__(256) void bucket_scatter(const int* __restrict__ src,
                                                      const int* __restrict__ dst,
                                                      const int* __restrict__ gboff,
                                                      const int* __restrict__ relBase,
                                                      int2* __restrict__ eb,
                                                      int E, int N, int NB) {
    __shared__ int cur[256];
    int t = threadIdx.x, blk = blockIdx.x;
    if (t < NB) cur[t] = gboff[t] + relBase[blk * NB + t];
    __syncthreads();
    int e0 = blk * EPB + t;
#pragma unroll 4
    for (int k = 0; k < EPB / 256; ++k) {
        int e = e0 + k * 256;
        if (e < E) {
            int d = dst[e];
            if ((unsigned)d < (unsigned)N) {
                int pos = atomicAdd(&cur[d >> 9], 1);
                eb[pos] = make_int2(src[e], d);
            }
        }
    }
}

// P3: one 512-thread block per bucket; local per-node count + LDS scan ->
// offs for the bucket's 512 nodes, then csr writes in a ~32KB window.
__global__ __launch_bounds__(512) void csr_build(const int2* __restrict__ eb,
                                                 const int* __restrict__ gboff,
                                                 int* __restrict__ offs,
                                                 int* __restrict__ csr,
                                                 int N, int NB) {
    __shared__ int lcnt[512];
    __shared__ int sm[512];
    __shared__ int cur[512];
    int t = threadIdx.x, b = blockIdx.x;
    lcnt[t] = 0;
    __syncthreads();
    int s0 = gboff[b], s1 = gboff[b + 1];
    for (int e = s0 + t; e < s1; e += 512) atomicAdd(&lcnt[eb[e].y & 511], 1);
    __syncthreads();
    int v = lcnt[t];
    sm[t] = v;
    __syncthreads();
#pragma unroll
    for (int o = 1; o < 512; o <<= 1) {
        int u = (t >= o) ? sm[t - o] : 0;
        __syncthreads();
        sm[t] += u;
        __syncthreads();
    }
    int base = gboff[b] + sm[t] - v;   // exclusive
    cur[t] = base;
    int n0 = (b << 9) + t;
    if (n0 < N) offs[n0] = base;
    if (b == NB - 1 && t == 0) offs[N] = gboff[NB];
    __syncthreads();
    for (int e = s0 + t; e < s1; e += 512) {
        int2 p = eb[e];
        int pos = atomicAdd(&cur[p.y & 511], 1);
        csr[pos] = p.x;
    }
}

// ===== Dense GEMM: bf16 mirror + fused attention scores (+fp32 out optional) =====
// Layer GEMMs: OUT=nullptr (fp32 h never materialized), HB=bf16 h, ASrc/ADst
// produce sSt/sDt (SoA by head). Residual GEMM: OUT=out, accumulate, no scores.

__global__ __launch_bounds__(256) void gemm128(const float* __restrict__ X,
                                               const float* __restrict__ W,
                                               float* __restrict__ OUT,
                                               unsigned short* __restrict__ HB,
                                               const float* __restrict__ bias,
                                               int accumulate,
                                               const float* __restrict__ ASrc,
                                               const float* __restrict__ ADst,
                                               float* __restrict__ sSt,
                                               float* __restrict__ sDt, int N) {
    __shared__ float Xs[32][128];
    __shared__ float Ws[64][128];
    int t = threadIdx.x;
    int row0 = blockIdx.x << 5;
    {
        const float4* xg = (const float4*)(X + (size_t)row0 * 128);
        float4* xs = (float4*)&Xs[0][0];
#pragma unroll
        for (int i = 0; i < 4; ++i) xs[t + 256 * i] = xg[t + 256 * i];
    }
    int cx = t & 31, ry = t >> 5;
    int c0 = cx << 2, r0 = ry << 2;
    float acc[4][4] = {};
#pragma unroll 1
    for (int ph = 0; ph < 2; ++ph) {
        __syncthreads();
        {
            const float4* wg = (const float4*)(W + (size_t)ph * 64 * 128);
            float4* ws = (float4*)&Ws[0][0];
#pragma unroll
            for (int i = 0; i < 8; ++i) ws[t + 256 * i] = wg[t + 256 * i];
        }
        __syncthreads();
#pragma unroll 4
        for (int k4 = 0; k4 < 16; ++k4) {
            float4 a[4], b[4];
#pragma unroll
            for (int i = 0; i < 4; ++i)
                a[i] = *(const float4*)&Xs[r0 + i][(ph << 6) + (k4 << 2)];
#pragma unroll
            for (int kk = 0; kk < 4; ++kk)
                b[kk] = *(const float4*)&Ws[(k4 << 2) + kk][c0];
#pragma unroll
            for (int i = 0; i < 4; ++i) {
                acc[i][0] = fmaf(a[i].x, b[0].x, acc[i][0]);
                acc[i][1] = fmaf(a[i].x, b[0].y, acc[i][1]);
                acc[i][2] = fmaf(a[i].x, b[0].z, acc[i][2]);
                acc[i][3] = fmaf(a[i].x, b[0].w, acc[i][3]);
                acc[i][0] = fmaf(a[i].y, b[1].x, acc[i][0]);
                acc[i][1] = fmaf(a[i].y, b[1].y, acc[i][1]);
                acc[i][2] = fmaf(a[i].y, b[1].z, acc[i][2]);
                acc[i][3] = fmaf(a[i].y, b[1].w, acc[i][3]);
                acc[i][0] = fmaf(a[i].z, b[2].x, acc[i][0]);
                acc[i][1] = fmaf(a[i].z, b[2].y, acc[i][1]);
                acc[i][2] = fmaf(a[i].z, b[2].z, acc[i][2]);
                acc[i][3] = fmaf(a[i].z, b[2].w, acc[i][3]);
                acc[i][0] = fmaf(a[i].w, b[3].x, acc[i][0]);
                acc[i][1] = fmaf(a[i].w, b[3].y, acc[i][1]);
                acc[i][2] = fmaf(a[i].w, b[3].z, acc[i][2]);
                acc[i][3] = fmaf(a[i].w, b[3].w, acc[i][3]);
            }
        }
    }
    float4 bv = make_float4(0.f, 0.f, 0.f, 0.f);
    if (bias) bv = *(const float4*)&bias[c0];
    float4 sa = make_float4(0.f, 0.f, 0.f, 0.f), da = sa;
    if (ASrc) {
        sa = *(const float4*)&ASrc[c0];
        da = *(const float4*)&ADst[c0];
    }
#pragma unroll
    for (int i = 0; i < 4; ++i) {
        size_t row = (size_t)(row0 + r0 + i);
        float4 o;
        o.x = acc[i][0] + bv.x;
        o.y = acc[i][1] + bv.y;
        o.z = acc[i][2] + bv.z;
        o.w = acc[i][3] + bv.w;
        if (accumulate) {
            const float4 old = *(const float4*)(OUT + row * 128 + c0);
            o.x += old.x; o.y += old.y; o.z += old.z; o.w += old.w;
        }
        if (OUT) *(float4*)(OUT + row * 128 + c0) = o;
        if (HB) {
            ushort4 hv;
            hv.x = f2bf(o.x); hv.y = f2bf(o.y); hv.z = f2bf(o.z); hv.w = f2bf(o.w);
            *(ushort4*)(HB + row * 128 + c0) = hv;
        }
        if (ASrc) {
            // per-head dot over this thread's 4 channels, reduce over the
            // 8 threads (cx bits 0..2) sharing (row, head=cx>>3)
            float ps = o.x * sa.x + o.y * sa.y + o.z * sa.z + o.w * sa.w;
            float pd = o.x * da.x + o.y * da.y + o.z * da.z + o.w * da.w;
            ps += __shfl_xor(ps, 1); pd += __shfl_xor(pd, 1);
            ps += __shfl_xor(ps, 2); pd += __shfl_xor(pd, 2);
            ps += __shfl_xor(ps, 4); pd += __shfl_xor(pd, 4);
            if ((cx & 7) == 0) {
                size_t sidx = (size_t)(cx >> 3) * N + row;
                sSt[sidx] = ps;
                sDt[sidx] = pd;
            }
        }
    }
}

// ============ fused softmax-weight + gather-accumulate (v5) ============
// One wave per dst node. Consumer role: cl=lane&31 owns channels 4cl..4cl+3
// (head hd=cl>>3); half=lane>>5 takes edge i+half of each pair. Weight role:
// lane = whead*16+sub computes w(edge lo+sub, whead). Inner chunk is a FIXED
// 8-pair fully-unrolled loop (8 independent uint2 gathers in flight); tail
// lanes have spre=0 (row-0 load, L1-hot) and w=0. No max-subtraction:
// |scores| <~ 2, exp safe, softmax shift-invariant. Self row from bf16 hb.

__global__ __launch_bounds__(256) void agg5_kernel(const unsigned short* __restrict__ hb,
                                                   const float* __restrict__ sSt,
                                                   const float* __restrict__ sDt,
                                                   const int* __restrict__ offs,
                                                   const int* __restrict__ csr,
                                                   const float* __restrict__ bias,
                                                   float* __restrict__ out,
                                                   int do_relu, int N) {
    int n = (blockIdx.x << 2) + (threadIdx.x >> 6);
    if (n >= N) return;
    int lane = threadIdx.x & 63;
    int half = lane >> 5;
    int cl = lane & 31;
    int hd = cl >> 3;
    int whead = lane >> 4;
    int sub = lane & 15;

    size_t wb = (size_t)whead * N;
    float sdh = sDt[wb + n];
    float selfw = __expf(leaky1(sSt[wb + n] + sdh));

    float4 acc = make_float4(0.f, 0.f, 0.f, 0.f);
    float wsum = 0.f;

    int off = offs[n], end = offs[n + 1];
    for (int base = off; base < end; base += 64) {
        int idx = base + lane;
        int spre = (idx < end) ? csr[idx] : 0;
        int cnt = min(64, end - base);
#pragma unroll 1
        for (int lo = 0; lo < cnt; lo += 16) {
            float w = 0.f;
            {
                int s2 = __shfl(spre, lo + sub);
                if (lo + sub < cnt) w = __expf(leaky1(sSt[wb + s2] + sdh));
            }
            wsum += w;
#pragma unroll
            for (int i = 0; i < 16; i += 2) {
                int sj = __shfl(spre, lo + i + half);
                float wj = __shfl(w, (hd << 4) + i + half);   // 0 past tail
                uint2 v = *(const uint2*)(hb + (size_t)sj * 128 + 4 * cl);
                acc.x = fmaf(wj, __uint_as_float(v.x << 16), acc.x);
                acc.y = fmaf(wj, __uint_as_float(v.x & 0xffff0000u), acc.y);
                acc.z = fmaf(wj, __uint_as_float(v.y << 16), acc.z);
                acc.w = fmaf(wj, __uint_as_float(v.y & 0xffff0000u), acc.w);
            }
        }
    }
    acc.x += __shfl_xor(acc.x, 32);
    acc.y += __shfl_xor(acc.y, 32);
    acc.z += __shfl_xor(acc.z, 32);
    acc.w += __shfl_xor(acc.w, 32);
#pragma unroll
    for (int o = 8; o > 0; o >>= 1) wsum += __shfl_xor(wsum, o);
    float denom = wsum + selfw;
    float iv = 1.0f / __shfl(denom, hd << 4);
    float sw = __shfl(selfw, hd << 4);

    if (half == 0) {
        uint2 hv = *(const uint2*)(hb + (size_t)n * 128 + 4 * cl);
        float4 hs;
        hs.x = __uint_as_float(hv.x << 16);
        hs.y = __uint_as_float(hv.x & 0xffff0000u);
        hs.z = __uint_as_float(hv.y << 16);
        hs.w = __uint_as_float(hv.y & 0xffff0000u);
        float4 bvv = *(const float4*)(bias + 4 * cl);
        float4 o;
        o.x = fmaf(fmaf(sw, hs.x, acc.x), iv, bvv.x);
        o.y = fmaf(fmaf(sw, hs.y, acc.y), iv, bvv.y);
        o.z = fmaf(fmaf(sw, hs.z, acc.z), iv, bvv.z);
        o.w = fmaf(fmaf(sw, hs.w, acc.w), iv, bvv.w);
        if (do_relu) {
            o.x = fmaxf(o.x, 0.f); o.y = fmaxf(o.y, 0.f);
            o.z = fmaxf(o.z, 0.f); o.w = fmaxf(o.w, 0.f);
        }
        *(float4*)(out + (size_t)n * 128 + 4 * cl) = o;
    }
}

// ================= host =================

extern "C" void kernel_launch(void* const* d_in, const int* in_sizes, int n_in,
                              void* d_out, int out_size, void* d_ws, size_t ws_size,
                              hipStream_t stream) {
    const float* x   = (const float*)d_in[0];
    const int*   ei  = (const int*)d_in[1];
    const float* W1  = (const float*)d_in[2];
    const float* a1s = (const float*)d_in[3];
    const float* a1d = (const float*)d_in[4];
    const float* b1  = (const float*)d_in[5];
    const float* W2  = (const float*)d_in[6];
    const float* a2s = (const float*)d_in[7];
    const float* a2d = (const float*)d_in[8];
    const float* b2  = (const float*)d_in[9];
    const float* Wr  = (const float*)d_in[10];
    const float* br  = (const float*)d_in[11];
    float* out = (float*)d_out;

    int N = in_sizes[0] / 128;
    int E = in_sizes[1] / 2;
    const int* src = ei;
    const int* dst = ei + E;
    int NB = (N + 511) >> 9;               // 196 buckets of 512 nodes
    int ebl = (E + EPB - 1) / EPB;         // 391 blocks in P1/P2

    char* w = (char*)d_ws;
    size_t p = 0;
    auto take = [&](size_t bytes) -> char* {
        char* r = w + p;
        p = (p + bytes + 255) & ~(size_t)255;
        return r;
    };
    float* bufB = (float*)take((size_t)N * 128 * 4);                  // h1 fp32
    unsigned short* hb = (unsigned short*)take((size_t)N * 128 * 2);  // h bf16
    float* sSt  = (float*)take((size_t)N * 4 * 4);
    float* sDt  = (float*)take((size_t)N * 4 * 4);
    int* gcnt   = (int*)take((size_t)256 * 4);
    int* offs   = (int*)take((size_t)(N + 1) * 4);
    int* gboff  = (int*)take((size_t)257 * 4);
    int* relBase = (int*)take((size_t)ebl * NB * 4);
    int2* eb    = (int2*)take((size_t)E * 8);
    int* csr    = (int*)take((size_t)E * 4);

    hipMemsetAsync(gcnt, 0, 256 * 4, stream);

    bucket_hist<<<ebl, 256, 0, stream>>>(dst, gcnt, relBase, E, N, NB);
    scan_buckets<<<1, 256, 0, stream>>>(gcnt, gboff, NB);
    bucket_scatter<<<ebl, 256, 0, stream>>>(src, dst, gboff, relBase, eb, E, N, NB);
    csr_build<<<NB, 512, 0, stream>>>(eb, gboff, offs, csr, N, NB);

    int gb = N / 32;
    int ab = (N + 3) / 4;

    // layer 1: gemm emits bf16 h + scores only (no fp32 h)
    gemm128<<<gb, 256, 0, stream>>>(x, W1, nullptr, hb, nullptr, 0, a1s, a1d, sSt, sDt, N);
    agg5_kernel<<<ab, 256, 0, stream>>>(hb, sSt, sDt, offs, csr, b1, bufB, 1, N);
    // layer 2
    gemm128<<<gb, 256, 0, stream>>>(bufB, W2, nullptr, hb, nullptr, 0, a2s, a2d, sSt, sDt, N);
    agg5_kernel<<<ab, 256, 0, stream>>>(hb, sSt, sDt, offs, csr, b2, out, 0, N);
    // residual: out += x @ Wr + br
    gemm128<<<gb, 256, 0, stream>>>(x, Wr, out, nullptr, br, 1, nullptr, nullptr, nullptr, nullptr, N);
}